// Round 1
// baseline (120.249 us; speedup 1.0000x reference)
//
#include <hip/hip_runtime.h>

// Guided filter r=5, B=8 C=3 H=W=512 fp32 — single fused kernel, round 8.
// Per 64x14 output tile:
//   P1:  load x,y with 2R halo, vertical 11-sums of (x,y,xy,xx) via register
//        sliding window -> LDS v4[24][97sw] (float4).
//   P2a: horizontal 11-sums, width-8 chunks with a 10-deep float4 REGISTER RING
//        (trailing edge from registers, only leading edge read from LDS)
//        -> A,b DEFERRED into registers (pres[8]) — no LDS writes yet.
//   P2b: after a barrier (all v4 reads drained), write A,b -> ab2 which now
//        ALIASES the v4 region (v4 dead). This cuts LDS 53,184 -> 37,248 B
//        => 4 blocks/CU (was 3), 16 waves/CU.
//   P3:  vertical 11-sums of (A,b), register ring -> vab at +16,000 (disjoint
//        from ab2, both inside the old v4 footprint).
//   P4:  horizontal 11-sums + epilogue, register ring;
//        out = meanA*x + meanb, x re-read from global (L3-hot, coalesced).
// Bank floors (words mod 32), PB(c)=c+(c>>3), V4STR=97 (388w==4), ABSTR=83 (166w==6):
//   P1 writes: consec cc, 4*PB(cc) -> {0,4,..,28} x2 -> floor.
//   P2a reads: 16-lane group same chunk, consec r -> const + 4r -> floor.
//   P2b writes: fixed i, lanes (r,ch): 6r mod 32 (2-way at r,r+16 = free)
//              + 2*PB(8ch+i) distinct per ch -> ~2-way -> free.
//   P3/P4: consec ac / c0=4ch b64 -> <=2-3 words/bank.
// Base alignment preserved: ab2 @0 (mod128==0, same as old 37,248), vab @16,000
// (=125*128) -> prior bank analyses unchanged.
// LDS 37,248 B -> 4 blocks/CU; __launch_bounds__(256,4) caps VGPR at 128.

#define R    5
#define TX   64
#define TY   14
#define IMG  512
#define AROWS (TY + 2 * R)   // 24
#define ACOLS (TX + 2 * R)   // 74
#define XCOLS (TX + 4 * R)   // 84
#define V4STR 97             // float4 row stride, PB(83)=93
#define ABSTR 83             // float2 row stride, PB(73)=82
#define OFF_VAB 16000                            // 125*128, past ab2's 15,936
#define SMEM_TOTAL (AROWS * V4STR * 16)          // 37,248

#define PB(c) ((c) + ((c) >> 3))

__device__ __forceinline__ float ccnt(int g) {
    int lo = max(g - R, 0), hi = min(g + R, IMG - 1);
    return (float)(hi - lo + 1);
}

__global__ __launch_bounds__(256, 4) void guided_fused(
        const float* __restrict__ x, const float* __restrict__ y,
        float* __restrict__ out) {
    __shared__ __align__(16) unsigned char smem[SMEM_TOTAL];
    float4 (*v4)[V4STR] = (float4(*)[V4STR])smem;
    float2 (*ab2)[ABSTR] = (float2(*)[ABSTR])smem;              // aliases v4
    float2 (*vab)[ABSTR] = (float2(*)[ABSTR])(smem + OFF_VAB);  // disjoint from ab2

    const int plane = blockIdx.z;
    const int tx0 = blockIdx.x * TX;
    const int ty0 = blockIdx.y * TY;
    const int tid = threadIdx.x;
    const size_t pbase = (size_t)plane * IMG * IMG;
    const float* xp = x + pbase;
    const float* yp = y + pbase;
    const bool interior = (tx0 >= 2 * R) && (tx0 + TX + 2 * R - 1 < IMG) &&
                          (ty0 >= 2 * R) && (ty0 + TY + 2 * R - 1 < IMG);

    // ---- P1: vertical 11-sums at 84 cols x 24 A,b-rows. 3 segs x 8 rows.
    if (tid < 3 * XCOLS) {
        const int seg = tid / XCOLS;
        const int cc  = tid - seg * XCOLS;
        const int r0  = seg * 8;
        const int gx  = tx0 - 2 * R + cc;
        const int gy0 = ty0 - 2 * R + r0;

        float xv[18], yv[18];
        if (interior) {
            const float* xc = xp + (size_t)gy0 * IMG + gx;
            const float* yc = yp + (size_t)gy0 * IMG + gx;
#pragma unroll
            for (int j = 0; j < 18; ++j) {
                xv[j] = xc[(size_t)j * IMG];
                yv[j] = yc[(size_t)j * IMG];
            }
        } else {
            const bool xok = ((unsigned)gx < (unsigned)IMG);
#pragma unroll
            for (int j = 0; j < 18; ++j) {
                int gy = gy0 + j;
                bool ok = xok && ((unsigned)gy < (unsigned)IMG);
                size_t o = (size_t)gy * IMG + gx;
                xv[j] = ok ? xp[o] : 0.f;
                yv[j] = ok ? yp[o] : 0.f;
            }
        }
        float sx = 0.f, sy = 0.f, sxy = 0.f, sxx = 0.f;
#pragma unroll
        for (int j = 0; j < 11; ++j) {
            sx += xv[j]; sy += yv[j];
            sxy += xv[j] * yv[j]; sxx += xv[j] * xv[j];
        }
        v4[r0][PB(cc)] = make_float4(sx, sy, sxy, sxx);
#pragma unroll
        for (int s = 1; s < 8; ++s) {
            float xn = xv[s + 10], yn = yv[s + 10];
            float xo = xv[s - 1],  yo = yv[s - 1];
            sx  += xn - xo;
            sy  += yn - yo;
            sxy += xn * yn - xo * yo;
            sxx += xn * xn - xo * xo;
            v4[r0 + s][PB(cc)] = make_float4(sx, sy, sxy, sxx);
        }
    }
    __syncthreads();

    // ---- P2a: horizontal 11-sums -> A,b on 74x24, DEFERRED to registers.
    // 240 threads: chunk ch = tid/24 (0..9, width 8), row r = tid%24.
    int p2_r = 0, p2_c0 = 0, p2_nout = 0;
    float2 pres[8];
    if (tid < 240) {
        const int ch = tid / 24;
        const int r  = tid - ch * 24;
        const int c0 = 8 * ch;
        const int nout = min(8, ACOLS - c0);   // 8, or 2 for ch=9
        p2_r = r; p2_c0 = c0; p2_nout = nout;

        float4 ring[10];
#pragma unroll
        for (int d = 0; d < 10; ++d) ring[d] = v4[r][PB(c0 + d)];
        float sx = 0.f, sy = 0.f, sxy = 0.f, sxx = 0.f;
#pragma unroll
        for (int d = 0; d < 10; ++d) {
            sx += ring[d].x; sy += ring[d].y;
            sxy += ring[d].z; sxx += ring[d].w;
        }
        const int ay = ty0 - R + r;
        const float cy = ccnt(ay);
        const bool ayok = ((unsigned)ay < (unsigned)IMG);
#pragma unroll
        for (int i = 0; i < 8; ++i) {
            if (i < nout) {
                float4 lead = v4[r][PB(c0 + 10 + i)];
                sx += lead.x; sy += lead.y; sxy += lead.z; sxx += lead.w;
                if (i > 0) {
                    float4 o = ring[(i > 0) ? (i - 1) : 0];
                    sx -= o.x; sy -= o.y; sxy -= o.z; sxx -= o.w;
                }
                const int ac = c0 + i;
                const int ax = tx0 - R + ac;
                float A = 0.f, bb = 0.f;
                if (interior || (ayok && ((unsigned)ax < (unsigned)IMG))) {
                    float inv = interior ? (1.0f / 121.0f)
                                         : __builtin_amdgcn_rcpf(cy * ccnt(ax));
                    float mx = sx * inv, my = sy * inv;
                    float cov = sxy * inv - mx * my;
                    float var = sxx * inv - mx * mx;
                    A = cov * __builtin_amdgcn_rcpf(var + 0.01f);
                    bb = my - A * mx;
                }
                pres[i] = make_float2(A, bb);
            }
        }
    }
    __syncthreads();   // all v4 reads drained -> safe to overwrite with ab2

    // ---- P2b: write deferred A,b into ab2 (aliases v4 region).
    if (tid < 240) {
#pragma unroll
        for (int i = 0; i < 8; ++i) {
            if (i < p2_nout) ab2[p2_r][PB(p2_c0 + i)] = pres[i];
        }
    }
    __syncthreads();

    // ---- P3: vertical 11-sums of (A,b): 74 cols x 2 segs of 7 rows. Ring.
    if (tid < 2 * ACOLS) {
        const int seg = (tid >= ACOLS) ? 1 : 0;
        const int ac = tid - seg * ACOLS;
        const int r0 = seg * 7;
        float2 ring[10];
#pragma unroll
        for (int d = 0; d < 10; ++d) ring[d] = ab2[r0 + d][PB(ac)];
        float sa = 0.f, sb = 0.f;
#pragma unroll
        for (int d = 0; d < 10; ++d) { sa += ring[d].x; sb += ring[d].y; }
#pragma unroll
        for (int s = 0; s < 7; ++s) {
            float2 lead = ab2[r0 + 10 + s][PB(ac)];
            sa += lead.x; sb += lead.y;
            if (s > 0) {
                float2 o = ring[(s > 0) ? (s - 1) : 0];
                sa -= o.x; sb -= o.y;
            }
            vab[r0 + s][PB(ac)] = make_float2(sa, sb);
        }
    }
    __syncthreads();

    // ---- P4: horizontal 11-sums + epilogue. 14 rows x 16 width-4 chunks. Ring.
    if (tid < TY * 16) {
        const int oy = tid >> 4;
        const int ch = tid & 15;
        const int c0 = 4 * ch;
        const int gy = ty0 + oy;
        if (gy < IMG) {
            float2 ring[10];
#pragma unroll
            for (int d = 0; d < 10; ++d) ring[d] = vab[oy][PB(c0 + d)];
            float sa = 0.f, sb = 0.f;
#pragma unroll
            for (int d = 0; d < 10; ++d) { sa += ring[d].x; sb += ring[d].y; }
            const float cy = ccnt(gy);
            const size_t obase = (size_t)gy * IMG + tx0 + c0;
            const float4 xv4 = *reinterpret_cast<const float4*>(&xp[obase]);
            const float xv[4] = {xv4.x, xv4.y, xv4.z, xv4.w};
            float res[4];
#pragma unroll
            for (int i = 0; i < 4; ++i) {
                float2 lead = vab[oy][PB(c0 + 10 + i)];
                sa += lead.x; sb += lead.y;
                if (i > 0) {
                    float2 o = ring[(i > 0) ? (i - 1) : 0];
                    sa -= o.x; sb -= o.y;
                }
                float inv = interior ? (1.0f / 121.0f)
                                     : __builtin_amdgcn_rcpf(cy * ccnt(tx0 + c0 + i));
                res[i] = (sa * inv) * xv[i] + (sb * inv);
            }
            *reinterpret_cast<float4*>(&out[pbase + obase]) =
                make_float4(res[0], res[1], res[2], res[3]);
        }
    }
}

extern "C" void kernel_launch(void* const* d_in, const int* in_sizes, int n_in,
                              void* d_out, int out_size, void* d_ws, size_t ws_size,
                              hipStream_t stream) {
    const float* x = (const float*)d_in[0];
    const float* y = (const float*)d_in[1];
    float* out = (float*)d_out;

    const int planes = in_sizes[0] / (IMG * IMG);  // 24

    dim3 grid(IMG / TX, (IMG + TY - 1) / TY, planes);  // 8 x 37 x 24
    guided_fused<<<grid, 256, 0, stream>>>(x, y, out);
}

// Round 2
// 118.795 us; speedup vs baseline: 1.0122x; 1.0122x over previous
//
#include <hip/hip_runtime.h>

// Guided filter r=5, B=8 C=3 H=W=512 fp32 — single fused kernel, round 9.
// TY=16 (512=32x16: no tail waste, grid 8x32x24=6144 blocks, was 7104).
// Per 64x16 output tile:
//   P1:  load x,y with 2R halo, vertical 11-sums of (x,y,xy,xx) via register
//        sliding window -> LDS v4[26][97sw] (float4). 3 segs (9/9/8 rows).
//   P2a: horizontal 11-sums, width-10 chunks (208 thr) with a 10-deep float4
//        REGISTER RING -> A,b DEFERRED into registers (pres[10]) — no LDS
//        writes yet. 2.0 b128 reads/output (was 2.25).
//   P2b: after barrier (v4 reads drained), write A,b -> ab2 ALIASING v4.
//   P3:  vertical 11-sums of (A,b), register ring, 2 segs x 8 rows -> vab
//        at +17,280 (disjoint from ab2, inside dead v4 footprint).
//   P4:  horizontal 11-sums + epilogue, 16 rows x 16 chunks = 256 thr (full
//        block), no gy bound needed; out = meanA*x + meanb, x re-read global.
// Bank floors (words mod 32), PB(c)=c+(c>>3), V4STR=97 (388w==4), ABSTR=83 (166w==6):
//   P1 writes: consec cc, 4*PB(cc) -> {0,4,..,28} x2 -> floor.
//   P2a reads: 26-lane group same chunk, consec r -> const + 4r -> ~uniform.
//   P2b writes: fixed i, lanes (r,ch): 6r mod 32 (2-way free) + distinct ch.
//   P3/P4: consec ac / c0=4ch b64 -> <=2-3 words/bank.
// ab2 @0 (mod128==0), vab @17,280 (=135*128) -> bank alignments preserved.
// LDS 40,352 B -> 4 blocks/CU; __launch_bounds__(256,4) caps VGPR at 128.

#define R    5
#define TX   64
#define TY   16
#define IMG  512
#define AROWS (TY + 2 * R)   // 26
#define ACOLS (TX + 2 * R)   // 74
#define XCOLS (TX + 4 * R)   // 84
#define V4STR 97             // float4 row stride
#define ABSTR 83             // float2 row stride
#define OFF_VAB 17280                            // 135*128 >= ab2's 17,264
#define SMEM_TOTAL (AROWS * V4STR * 16)          // 40,352

#define PB(c) ((c) + ((c) >> 3))

__device__ __forceinline__ float ccnt(int g) {
    int lo = max(g - R, 0), hi = min(g + R, IMG - 1);
    return (float)(hi - lo + 1);
}

__global__ __launch_bounds__(256, 4) void guided_fused(
        const float* __restrict__ x, const float* __restrict__ y,
        float* __restrict__ out) {
    __shared__ __align__(16) unsigned char smem[SMEM_TOTAL];
    float4 (*v4)[V4STR] = (float4(*)[V4STR])smem;
    float2 (*ab2)[ABSTR] = (float2(*)[ABSTR])smem;              // aliases v4
    float2 (*vab)[ABSTR] = (float2(*)[ABSTR])(smem + OFF_VAB);  // disjoint from ab2

    const int plane = blockIdx.z;
    const int tx0 = blockIdx.x * TX;
    const int ty0 = blockIdx.y * TY;
    const int tid = threadIdx.x;
    const size_t pbase = (size_t)plane * IMG * IMG;
    const float* xp = x + pbase;
    const float* yp = y + pbase;
    const bool interior = (tx0 >= 2 * R) && (tx0 + TX + 2 * R - 1 < IMG) &&
                          (ty0 >= 2 * R) && (ty0 + TY + 2 * R - 1 < IMG);

    // ---- P1: vertical 11-sums at 84 cols x 26 A,b-rows. 3 segs (9/9/8 rows).
    if (tid < 3 * XCOLS) {
        const int seg = tid / XCOLS;
        const int cc  = tid - seg * XCOLS;
        const int r0  = seg * 9;              // 0, 9, 18
        const int gx  = tx0 - 2 * R + cc;
        const int gy0 = ty0 - 2 * R + r0;

        float xv[19], yv[19];
        if (interior) {
            const float* xc = xp + (size_t)gy0 * IMG + gx;
            const float* yc = yp + (size_t)gy0 * IMG + gx;
#pragma unroll
            for (int j = 0; j < 19; ++j) {
                xv[j] = xc[(size_t)j * IMG];
                yv[j] = yc[(size_t)j * IMG];
            }
        } else {
            const bool xok = ((unsigned)gx < (unsigned)IMG);
#pragma unroll
            for (int j = 0; j < 19; ++j) {
                int gy = gy0 + j;
                bool ok = xok && ((unsigned)gy < (unsigned)IMG);
                size_t o = (size_t)gy * IMG + gx;
                xv[j] = ok ? xp[o] : 0.f;
                yv[j] = ok ? yp[o] : 0.f;
            }
        }
        float sx = 0.f, sy = 0.f, sxy = 0.f, sxx = 0.f;
#pragma unroll
        for (int j = 0; j < 11; ++j) {
            sx += xv[j]; sy += yv[j];
            sxy += xv[j] * yv[j]; sxx += xv[j] * xv[j];
        }
        v4[r0][PB(cc)] = make_float4(sx, sy, sxy, sxx);
#pragma unroll
        for (int s = 1; s < 9; ++s) {
            if (r0 + s < AROWS) {   // seg2 stops at 8 rows
                float xn = xv[s + 10], yn = yv[s + 10];
                float xo = xv[s - 1],  yo = yv[s - 1];
                sx  += xn - xo;
                sy  += yn - yo;
                sxy += xn * yn - xo * yo;
                sxx += xn * xn - xo * xo;
                v4[r0 + s][PB(cc)] = make_float4(sx, sy, sxy, sxx);
            }
        }
    }
    __syncthreads();

    // ---- P2a: horizontal 11-sums -> A,b on 74x26, DEFERRED to registers.
    // 208 threads: chunk ch = tid/26 (0..7, width 10), row r = tid%26. Ring.
    int p2_r = 0, p2_c0 = 0, p2_nout = 0;
    float2 pres[10];
    if (tid < 8 * AROWS) {
        const int ch = tid / AROWS;
        const int r  = tid - ch * AROWS;
        const int c0 = 10 * ch;
        const int nout = min(10, ACOLS - c0);   // 10, or 4 for ch=7
        p2_r = r; p2_c0 = c0; p2_nout = nout;

        float4 ring[10];
#pragma unroll
        for (int d = 0; d < 10; ++d) ring[d] = v4[r][PB(c0 + d)];
        float sx = 0.f, sy = 0.f, sxy = 0.f, sxx = 0.f;
#pragma unroll
        for (int d = 0; d < 10; ++d) {
            sx += ring[d].x; sy += ring[d].y;
            sxy += ring[d].z; sxx += ring[d].w;
        }
        const int ay = ty0 - R + r;
        const float cy = ccnt(ay);
        const bool ayok = ((unsigned)ay < (unsigned)IMG);
#pragma unroll
        for (int i = 0; i < 10; ++i) {
            if (i < nout) {
                float4 lead = v4[r][PB(c0 + 10 + i)];
                sx += lead.x; sy += lead.y; sxy += lead.z; sxx += lead.w;
                if (i > 0) {
                    float4 o = ring[(i > 0) ? (i - 1) : 0];
                    sx -= o.x; sy -= o.y; sxy -= o.z; sxx -= o.w;
                }
                const int ac = c0 + i;
                const int ax = tx0 - R + ac;
                float A = 0.f, bb = 0.f;
                if (interior || (ayok && ((unsigned)ax < (unsigned)IMG))) {
                    float inv = interior ? (1.0f / 121.0f)
                                         : __builtin_amdgcn_rcpf(cy * ccnt(ax));
                    float mx = sx * inv, my = sy * inv;
                    float cov = sxy * inv - mx * my;
                    float var = sxx * inv - mx * mx;
                    A = cov * __builtin_amdgcn_rcpf(var + 0.01f);
                    bb = my - A * mx;
                }
                pres[i] = make_float2(A, bb);
            }
        }
    }
    __syncthreads();   // all v4 reads drained -> safe to overwrite with ab2

    // ---- P2b: write deferred A,b into ab2 (aliases v4 region).
    if (tid < 8 * AROWS) {
#pragma unroll
        for (int i = 0; i < 10; ++i) {
            if (i < p2_nout) ab2[p2_r][PB(p2_c0 + i)] = pres[i];
        }
    }
    __syncthreads();

    // ---- P3: vertical 11-sums of (A,b): 74 cols x 2 segs of 8 rows. Ring.
    if (tid < 2 * ACOLS) {
        const int seg = (tid >= ACOLS) ? 1 : 0;
        const int ac = tid - seg * ACOLS;
        const int r0 = seg * 8;
        float2 ring[10];
#pragma unroll
        for (int d = 0; d < 10; ++d) ring[d] = ab2[r0 + d][PB(ac)];
        float sa = 0.f, sb = 0.f;
#pragma unroll
        for (int d = 0; d < 10; ++d) { sa += ring[d].x; sb += ring[d].y; }
#pragma unroll
        for (int s = 0; s < 8; ++s) {
            float2 lead = ab2[r0 + 10 + s][PB(ac)];
            sa += lead.x; sb += lead.y;
            if (s > 0) {
                float2 o = ring[(s > 0) ? (s - 1) : 0];
                sa -= o.x; sb -= o.y;
            }
            vab[r0 + s][PB(ac)] = make_float2(sa, sb);
        }
    }
    __syncthreads();

    // ---- P4: horizontal 11-sums + epilogue. 16 rows x 16 width-4 chunks,
    // 256 threads (full block). gy always < IMG (512 = 32*16).
    {
        const int oy = tid >> 4;
        const int ch = tid & 15;
        const int c0 = 4 * ch;
        const int gy = ty0 + oy;
        float2 ring[10];
#pragma unroll
        for (int d = 0; d < 10; ++d) ring[d] = vab[oy][PB(c0 + d)];
        float sa = 0.f, sb = 0.f;
#pragma unroll
        for (int d = 0; d < 10; ++d) { sa += ring[d].x; sb += ring[d].y; }
        const float cy = ccnt(gy);
        const size_t obase = (size_t)gy * IMG + tx0 + c0;
        const float4 xv4 = *reinterpret_cast<const float4*>(&xp[obase]);
        const float xv[4] = {xv4.x, xv4.y, xv4.z, xv4.w};
        float res[4];
#pragma unroll
        for (int i = 0; i < 4; ++i) {
            float2 lead = vab[oy][PB(c0 + 10 + i)];
            sa += lead.x; sb += lead.y;
            if (i > 0) {
                float2 o = ring[(i > 0) ? (i - 1) : 0];
                sa -= o.x; sb -= o.y;
            }
            float inv = interior ? (1.0f / 121.0f)
                                 : __builtin_amdgcn_rcpf(cy * ccnt(tx0 + c0 + i));
            res[i] = (sa * inv) * xv[i] + (sb * inv);
        }
        *reinterpret_cast<float4*>(&out[pbase + obase]) =
            make_float4(res[0], res[1], res[2], res[3]);
    }
}

extern "C" void kernel_launch(void* const* d_in, const int* in_sizes, int n_in,
                              void* d_out, int out_size, void* d_ws, size_t ws_size,
                              hipStream_t stream) {
    const float* x = (const float*)d_in[0];
    const float* y = (const float*)d_in[1];
    float* out = (float*)d_out;

    const int planes = in_sizes[0] / (IMG * IMG);  // 24

    dim3 grid(IMG / TX, IMG / TY, planes);  // 8 x 32 x 24
    guided_fused<<<grid, 256, 0, stream>>>(x, y, out);
}

// Round 3
// 117.737 us; speedup vs baseline: 1.0213x; 1.0090x over previous
//
#include <hip/hip_runtime.h>

// Guided filter r=5, B=8 C=3 H=W=512 fp32 — single fused kernel, round 10.
// TY=16 (grid 8x32x24 = 6144 blocks). ALL LDS accesses are affine:
// base computed once per thread, every indexed access = base + compile-time
// immediate (chunk starts c0 are multiples of 8, so PB(c0+d) = PB(c0) +
// d + (d>>3) with d an unroll constant).
//   P1:  load x,y with 2R halo, vertical 11-sums of (x,y,xy,xx), register
//        sliding window -> LDS v4[26][97sw] float4. 3 segs (9/9/8 rows).
//        (affine: fixed column, row offsets are 1552B imms)
//   P2a: horizontal 11-sums, 9 chunks (8x width-8 + 1x width-10, c0=8ch),
//        234 thr, 10-deep float4 register ring, reads ds_read_b128 base+imm
//        -> A,b DEFERRED in registers (pres[10]).
//   x-prefetch: P4 threads (tid<128) issue their 2 float4 x loads here —
//        2 phases ahead of use, L2 latency hidden under P2b+P3.
//   P2b: after barrier (v4 reads drained), write A,b -> ab2 ALIASING v4
//        (affine b64 writes).
//   P3:  vertical 11-sums of (A,b), register ring, 2 segs x 8 rows -> vab
//        at +17,280 (disjoint from ab2, inside dead v4 footprint). Affine.
//   P4:  horizontal 11-sums + epilogue, 16 rows x 8 width-8 chunks = 128 thr,
//        8 outputs/thread, affine b64 reads; out = meanA*x + meanb via the
//        prefetched x; 2x float4 stores.
// Bank floors (words mod 32), PB(c)=c+(c>>3), V4STR=97 (388w==4), ABSTR=83 (166w==6):
//   P1 writes: consec cc, 4*PB(cc) -> {0,4,..,28} x2 -> floor.
//   P2a reads: lanes (ch,r): 4r mod 32 + 36ch rot -> ~3-4 words/bank (floor).
//   P2b writes: 6r mod 32 (16 even residues) + 18ch rot -> ~2-way -> free.
//   P3: consec ac -> 2*PB(ac) spread -> ~2-3/bank. P4: 6oy+18ch even spread
//       -> ~4-way on a small op count (36 wave-ops).
// ab2 @0 (mod128==0), vab @17,280 (=135*128). LDS 40,352 B -> 4 blocks/CU.

#define R    5
#define TX   64
#define TY   16
#define IMG  512
#define AROWS (TY + 2 * R)   // 26
#define ACOLS (TX + 2 * R)   // 74
#define XCOLS (TX + 4 * R)   // 84
#define V4STR 97             // float4 row stride
#define ABSTR 83             // float2 row stride
#define OFF_VAB 17280                            // 135*128 >= ab2's 17,264
#define SMEM_TOTAL (AROWS * V4STR * 16)          // 40,352

#define PB(c)   ((c) + ((c) >> 3))
#define OFFD(d) ((d) + ((d) >> 3))   // PB(c0+d)-PB(c0) when c0%8==0

__device__ __forceinline__ float ccnt(int g) {
    int lo = max(g - R, 0), hi = min(g + R, IMG - 1);
    return (float)(hi - lo + 1);
}

__global__ __launch_bounds__(256, 4) void guided_fused(
        const float* __restrict__ x, const float* __restrict__ y,
        float* __restrict__ out) {
    __shared__ __align__(16) unsigned char smem[SMEM_TOTAL];
    float4 (*v4)[V4STR] = (float4(*)[V4STR])smem;
    float2 (*ab2)[ABSTR] = (float2(*)[ABSTR])smem;              // aliases v4
    float2 (*vab)[ABSTR] = (float2(*)[ABSTR])(smem + OFF_VAB);  // disjoint from ab2

    const int plane = blockIdx.z;
    const int tx0 = blockIdx.x * TX;
    const int ty0 = blockIdx.y * TY;
    const int tid = threadIdx.x;
    const size_t pbase = (size_t)plane * IMG * IMG;
    const float* xp = x + pbase;
    const float* yp = y + pbase;
    const bool interior = (tx0 >= 2 * R) && (tx0 + TX + 2 * R - 1 < IMG) &&
                          (ty0 >= 2 * R) && (ty0 + TY + 2 * R - 1 < IMG);

    // ---- P1: vertical 11-sums at 84 cols x 26 A,b-rows. 3 segs (9/9/8 rows).
    if (tid < 3 * XCOLS) {
        const int seg = tid / XCOLS;
        const int cc  = tid - seg * XCOLS;
        const int r0  = seg * 9;              // 0, 9, 18
        const int gx  = tx0 - 2 * R + cc;
        const int gy0 = ty0 - 2 * R + r0;

        float xv[19], yv[19];
        if (interior) {
            const float* xc = xp + (size_t)gy0 * IMG + gx;
            const float* yc = yp + (size_t)gy0 * IMG + gx;
#pragma unroll
            for (int j = 0; j < 19; ++j) {
                xv[j] = xc[(size_t)j * IMG];
                yv[j] = yc[(size_t)j * IMG];
            }
        } else {
            const bool xok = ((unsigned)gx < (unsigned)IMG);
#pragma unroll
            for (int j = 0; j < 19; ++j) {
                int gy = gy0 + j;
                bool ok = xok && ((unsigned)gy < (unsigned)IMG);
                size_t o = (size_t)gy * IMG + gx;
                xv[j] = ok ? xp[o] : 0.f;
                yv[j] = ok ? yp[o] : 0.f;
            }
        }
        float sx = 0.f, sy = 0.f, sxy = 0.f, sxx = 0.f;
#pragma unroll
        for (int j = 0; j < 11; ++j) {
            sx += xv[j]; sy += yv[j];
            sxy += xv[j] * yv[j]; sxx += xv[j] * xv[j];
        }
        float4* wp = &v4[r0][PB(cc)];
        wp[0] = make_float4(sx, sy, sxy, sxx);
#pragma unroll
        for (int s = 1; s < 9; ++s) {
            if (r0 + s < AROWS) {   // seg2 stops at 8 rows
                float xn = xv[s + 10], yn = yv[s + 10];
                float xo = xv[s - 1],  yo = yv[s - 1];
                sx  += xn - xo;
                sy  += yn - yo;
                sxy += xn * yn - xo * yo;
                sxx += xn * xn - xo * xo;
                wp[(size_t)s * V4STR] = make_float4(sx, sy, sxy, sxx);
            }
        }
    }
    __syncthreads();

    // ---- P2a: horizontal 11-sums -> A,b on 74x26, DEFERRED to registers.
    // 234 threads: chunk ch = tid/26 (0..8), row r = tid%26.
    // c0 = 8*ch (width 8; ch=8 has width 10, cols 64..73). All reads affine.
    int p2_r = 0, p2_pb0 = 0, p2_nout = 0;
    float2 pres[10];
    if (tid < 9 * AROWS) {
        const int ch = tid / AROWS;
        const int r  = tid - ch * AROWS;
        const int c0 = 8 * ch;
        const int nout = (ch == 8) ? 10 : 8;
        p2_r = r; p2_pb0 = 9 * ch; p2_nout = nout;

        const float4* bp = &v4[r][p2_pb0];
        float4 ring[10];
#pragma unroll
        for (int d = 0; d < 10; ++d) ring[d] = bp[OFFD(d)];
        float sx = 0.f, sy = 0.f, sxy = 0.f, sxx = 0.f;
#pragma unroll
        for (int d = 0; d < 10; ++d) {
            sx += ring[d].x; sy += ring[d].y;
            sxy += ring[d].z; sxx += ring[d].w;
        }
        const int ay = ty0 - R + r;
        const float cy = ccnt(ay);
        const bool ayok = ((unsigned)ay < (unsigned)IMG);
#pragma unroll
        for (int i = 0; i < 10; ++i) {
            if (i < nout) {
                float4 lead = bp[OFFD(10 + i)];
                sx += lead.x; sy += lead.y; sxy += lead.z; sxx += lead.w;
                if (i > 0) {
                    float4 o = ring[i - 1];
                    sx -= o.x; sy -= o.y; sxy -= o.z; sxx -= o.w;
                }
                const int ac = c0 + i;
                const int ax = tx0 - R + ac;
                float A = 0.f, bb = 0.f;
                if (interior || (ayok && ((unsigned)ax < (unsigned)IMG))) {
                    float inv = interior ? (1.0f / 121.0f)
                                         : __builtin_amdgcn_rcpf(cy * ccnt(ax));
                    float mx = sx * inv, my = sy * inv;
                    float cov = sxy * inv - mx * my;
                    float var = sxx * inv - mx * mx;
                    A = cov * __builtin_amdgcn_rcpf(var + 0.01f);
                    bb = my - A * mx;
                }
                pres[i] = make_float2(A, bb);
            }
        }
    }
    __syncthreads();   // all v4 reads drained -> safe to overwrite with ab2

    // ---- x-prefetch for P4 (2 phases ahead; L2 latency hides under P2b+P3).
    float4 xpa = make_float4(0.f, 0.f, 0.f, 0.f), xpb = xpa;
    size_t obase = 0;
    if (tid < TY * 8) {
        const int oy = tid >> 3;
        const int ch = tid & 7;
        obase = (size_t)(ty0 + oy) * IMG + tx0 + 8 * ch;
        xpa = *reinterpret_cast<const float4*>(&xp[obase]);
        xpb = *reinterpret_cast<const float4*>(&xp[obase + 4]);
    }

    // ---- P2b: write deferred A,b into ab2 (aliases v4 region). Affine.
    if (tid < 9 * AROWS) {
        float2* bw = &ab2[p2_r][p2_pb0];
#pragma unroll
        for (int i = 0; i < 10; ++i) {
            if (i < p2_nout) bw[OFFD(i)] = pres[i];
        }
    }
    __syncthreads();

    // ---- P3: vertical 11-sums of (A,b): 74 cols x 2 segs of 8 rows. Ring.
    if (tid < 2 * ACOLS) {
        const int seg = (tid >= ACOLS) ? 1 : 0;
        const int ac = tid - seg * ACOLS;
        const int r0 = seg * 8;
        const float2* rp = &ab2[r0][PB(ac)];
        float2* wp = &vab[r0][PB(ac)];
        float2 ring[10];
#pragma unroll
        for (int d = 0; d < 10; ++d) ring[d] = rp[(size_t)d * ABSTR];
        float sa = 0.f, sb = 0.f;
#pragma unroll
        for (int d = 0; d < 10; ++d) { sa += ring[d].x; sb += ring[d].y; }
#pragma unroll
        for (int s = 0; s < 8; ++s) {
            float2 lead = rp[(size_t)(10 + s) * ABSTR];
            sa += lead.x; sb += lead.y;
            if (s > 0) {
                float2 o = ring[s - 1];
                sa -= o.x; sb -= o.y;
            }
            wp[(size_t)s * ABSTR] = make_float2(sa, sb);
        }
    }
    __syncthreads();

    // ---- P4: horizontal 11-sums + epilogue. 16 rows x 8 width-8 chunks,
    // 128 threads, 8 outputs each. Affine b64 reads; prefetched x.
    if (tid < TY * 8) {
        const int oy = tid >> 3;
        const int ch = tid & 7;
        const int c0 = 8 * ch;
        const float2* vb = &vab[oy][9 * ch];   // PB(8ch) = 9ch
        float2 ring[10];
#pragma unroll
        for (int d = 0; d < 10; ++d) ring[d] = vb[OFFD(d)];
        float sa = 0.f, sb = 0.f;
#pragma unroll
        for (int d = 0; d < 10; ++d) { sa += ring[d].x; sb += ring[d].y; }
        const int gy = ty0 + oy;
        const float cy = ccnt(gy);
        const float xv[8] = {xpa.x, xpa.y, xpa.z, xpa.w,
                             xpb.x, xpb.y, xpb.z, xpb.w};
        float res[8];
#pragma unroll
        for (int i = 0; i < 8; ++i) {
            float2 lead = vb[OFFD(10 + i)];
            sa += lead.x; sb += lead.y;
            if (i > 0) {
                float2 o = ring[i - 1];
                sa -= o.x; sb -= o.y;
            }
            float inv = interior ? (1.0f / 121.0f)
                                 : __builtin_amdgcn_rcpf(cy * ccnt(tx0 + c0 + i));
            res[i] = (sa * inv) * xv[i] + (sb * inv);
        }
        *reinterpret_cast<float4*>(&out[pbase + obase]) =
            make_float4(res[0], res[1], res[2], res[3]);
        *reinterpret_cast<float4*>(&out[pbase + obase + 4]) =
            make_float4(res[4], res[5], res[6], res[7]);
    }
}

extern "C" void kernel_launch(void* const* d_in, const int* in_sizes, int n_in,
                              void* d_out, int out_size, void* d_ws, size_t ws_size,
                              hipStream_t stream) {
    const float* x = (const float*)d_in[0];
    const float* y = (const float*)d_in[1];
    float* out = (float*)d_out;

    const int planes = in_sizes[0] / (IMG * IMG);  // 24

    dim3 grid(IMG / TX, IMG / TY, planes);  // 8 x 32 x 24
    guided_fused<<<grid, 256, 0, stream>>>(x, y, out);
}